// Round 9
// baseline (192.824 us; speedup 1.0000x reference)
//
#include <hip/hip_runtime.h>
#include <hip/hip_bf16.h>
#include <hip/hip_fp16.h>
#include <type_traits>

#define NG 64          // number of graphs
#define FLAT 2904      // FC output width
#define K128 128       // inner dim for both GEMMs
#define BKB 256        // cols per bucket (col >> 8)

typedef _Float16 h4 __attribute__((ext_vector_type(4)));     // 8B
typedef _Float16 half8 __attribute__((ext_vector_type(8)));  // 16B MFMA frag
typedef float f32x4 __attribute__((ext_vector_type(4)));

// ---------------------------------------------------------------- utilities
__device__ __forceinline__ float4 ld4(const float* p) { return *(const float4*)p; }
__device__ __forceinline__ float4 ldh4(const _Float16* p) {
    h4 h = *(const h4*)p;
    return make_float4((float)h.x, (float)h.y, (float)h.z, (float)h.w);
}
__device__ __forceinline__ void sth4(_Float16* p, float4 v) {
    h4 h; h.x = (_Float16)v.x; h.y = (_Float16)v.y; h.z = (_Float16)v.z; h.w = (_Float16)v.w;
    *(h4*)p = h;
}
__device__ __forceinline__ float unpack_w(unsigned q) {
    return (float)__builtin_bit_cast(_Float16, (unsigned short)(q & 0xFFFFu));
}

// ------------------------------------------------- init: zero accum + both W converts
// block 0 zeroes bhist/bcursor/g/gcnt; all 96 blocks share the wconv work.
__global__ __launch_bounds__(256) void k_init(int* __restrict__ bhist,
                                              int* __restrict__ bcursor,
                                              float* __restrict__ g,
                                              int* __restrict__ gcnt,
                                              const float* __restrict__ W1,
                                              const float* __restrict__ W2,
                                              _Float16* __restrict__ Wt1,
                                              _Float16* __restrict__ Wt2) {
    int tid = threadIdx.x;
    if (blockIdx.x == 0) {
        bhist[tid] = 0; bcursor[tid] = 0;
        for (int i = tid; i < NG * 64; i += 256) g[i] = 0.f;
        if (tid < NG) gcnt[tid] = 0;
    }
    int idx = blockIdx.x * 256 + tid;
    if (idx < 128 * 128) {
        int n = idx % 128, k = idx / 128;
        Wt1[n * K128 + k] = (_Float16)W1[k * 128 + n];
    } else if (idx < 128 * 128 + 64 * 128) {
        int i = idx - 128 * 128;
        int n = i % 64, k = i / 64;
        Wt2[n * K128 + k] = (_Float16)W2[k * 64 + n];
    }
}

// ================================================================ CSR build
// bucket counting sort; per-block redundant 157-entry scan of bhist replaces
// the k_bscan dispatch. edata = (row<<16)|fp16(w'), w' = ew*dis[col].

__global__ __launch_bounds__(256) void k_bhist(const int* __restrict__ col,
                                               int* __restrict__ bhist, int E, int nbk) {
    __shared__ int h[BKB];
    int tid = threadIdx.x;
    for (int i = tid; i < nbk; i += 256) h[i] = 0;
    __syncthreads();
    int base = blockIdx.x * 1024 + tid * 4;
#pragma unroll
    for (int q = 0; q < 4; q++) {
        int e = base + q;
        if (e < E) atomicAdd(&h[col[e] >> 8], 1);
    }
    __syncthreads();
    for (int i = tid; i < nbk; i += 256) if (h[i]) atomicAdd(&bhist[i], h[i]);
}

__global__ __launch_bounds__(256) void k_bucket(const int* __restrict__ row,
                                                const int* __restrict__ col,
                                                const float* __restrict__ ew,
                                                const int* __restrict__ bhist,
                                                int* __restrict__ bcursor,
                                                uint2* __restrict__ bk, int E, int nbk) {
    __shared__ int part[256];
    __shared__ int h[BKB];
    __shared__ int cur[BKB];
    int tid = threadIdx.x;
    int gh = (tid < nbk) ? bhist[tid] : 0;
    part[tid] = gh;
    h[tid] = 0;
    __syncthreads();
    for (int off = 1; off < 256; off <<= 1) {
        int t = (tid >= off) ? part[tid - off] : 0;
        __syncthreads();
        part[tid] += t;
        __syncthreads();
    }
    int ex = part[tid] - gh;                  // exclusive global bucket base
    int base = blockIdx.x * 1024 + tid * 4;
    int c[4];
#pragma unroll
    for (int q = 0; q < 4; q++) {
        int e = base + q;
        c[q] = (e < E) ? col[e] : -1;
        if (c[q] >= 0) atomicAdd(&h[c[q] >> 8], 1);
    }
    __syncthreads();
    if (tid < nbk) cur[tid] = h[tid] ? ex + atomicAdd(&bcursor[tid], h[tid]) : 0;
    __syncthreads();
#pragma unroll
    for (int q = 0; q < 4; q++) {
        int e = base + q;
        if (c[q] >= 0) {
            int slot = atomicAdd(&cur[c[q] >> 8], 1);
            bk[slot] = make_uint2(((unsigned)c[q] << 16) | (unsigned)row[e],
                                  __float_as_uint(ew[e]));
        }
    }
}

// ---- fused: bucket base -> degree/count -> dis/rs -> edata
// Latency-shaped: 8-way batched pass-1 loads (MLP), wave-shuffle scans
// (6 shfl + 1 barrier instead of 8x2-barrier ladder), LDS edge cache.
__global__ __launch_bounds__(256) void k_colsedata(const uint2* __restrict__ bk,
                                                   const int* __restrict__ bhist,
                                                   float* __restrict__ dis,
                                                   int* __restrict__ rs,
                                                   unsigned* __restrict__ edata,
                                                   int N, int E, int nbk) {
    constexpr int CAP = 5120;          // 40 KB LDS edge cache (mean bucket 4096)
    __shared__ float sdeg[BKB];
    __shared__ int scnt[BKB];
    __shared__ int cur[BKB];
    __shared__ float sdis[BKB];
    __shared__ int wsum[4];
    __shared__ int sse[2];
    __shared__ uint2 ebuf[CAP];
    int b = blockIdx.x, tid = threadIdx.x;
    int lane = tid & 63, wv = tid >> 6;
    int gh = (tid < nbk) ? bhist[tid] : 0;
    sdeg[tid] = 0.f; scnt[tid] = 0;

    // ---- scan 1: inclusive scan of bhist over 256 threads (shuffle-based)
    int v = gh;
#pragma unroll
    for (int off = 1; off < 64; off <<= 1) {
        int t = __shfl_up(v, off);
        if (lane >= off) v += t;
    }
    if (lane == 63) wsum[wv] = v;
    __syncthreads();
    if (wv > 0) {
        int add = 0;
        for (int k = 0; k < wv; k++) add += wsum[k];
        v += add;
    }
    if (tid == b) { sse[0] = v - gh; sse[1] = v; }
    __syncthreads();
    int s = sse[0], e = sse[1];
    int n = e - s;

    // ---- pass 1: 8 independent loads in flight per iteration; LDS cache; deg/cnt
    for (int i0 = tid; i0 < n; i0 += 2048) {
        uint2 q[8]; bool gv[8];
#pragma unroll
        for (int u = 0; u < 8; u++) {
            int i = i0 + u * 256;
            gv[u] = i < n;
            if (gv[u]) q[u] = bk[s + i];
        }
#pragma unroll
        for (int u = 0; u < 8; u++) {
            if (gv[u]) {
                int i = i0 + u * 256;
                if (i < CAP) ebuf[i] = q[u];
                int c8 = (q[u].x >> 16) & 255;
                atomicAdd(&sdeg[c8], __uint_as_float(q[u].y));
                atomicAdd(&scnt[c8], 1);
            }
        }
    }
    __syncthreads();

    // ---- scan 2: inclusive scan of per-col counts (shuffle-based)
    int cnt = scnt[tid];
    int v2 = cnt;
#pragma unroll
    for (int off = 1; off < 64; off <<= 1) {
        int t = __shfl_up(v2, off);
        if (lane >= off) v2 += t;
    }
    if (lane == 63) wsum[wv] = v2;
    __syncthreads();
    if (wv > 0) {
        int add = 0;
        for (int k = 0; k < wv; k++) add += wsum[k];
        v2 += add;
    }
    float d  = rsqrtf(sdeg[tid] + 1.0f);
    int   r0 = s + v2 - cnt;
    int gcol = b * BKB + tid;
    if (gcol < N) { dis[gcol] = d; rs[gcol] = r0; }
    if (b == 0 && tid == 0) rs[N] = E;
    cur[tid] = r0; sdis[tid] = d;
    __syncthreads();

    // ---- pass 2: from LDS cache (fallback to global beyond CAP)
    for (int i = tid; i < n; i += 256) {
        uint2 q = (i < CAP) ? ebuf[i] : bk[s + i];
        int c8 = (q.x >> 16) & 255;
        unsigned r = q.x & 0xFFFFu;
        _Float16 wh = (_Float16)(__uint_as_float(q.y) * sdis[c8]);  // ew*dis[col]
        int pos = atomicAdd(&cur[c8], 1);
        edata[pos] = (r << 16) | (unsigned)__builtin_bit_cast(unsigned short, wh);
    }
}

// ------------------------------------------------- MFMA fp16 GEMM (layer1), dis epilogue
// out[r] = dis[r] * (A[r] @ W)  stored fp16.
__global__ __launch_bounds__(256) void k_gemm1(const float* __restrict__ A,
                                               const _Float16* __restrict__ Wt,
                                               const float* __restrict__ dis,
                                               _Float16* __restrict__ out, int M) {
    constexpr int NCOL = 128, AS = 136;
    __shared__ _Float16 Ah[64 * AS];
    __shared__ _Float16 Wh[NCOL * AS];

    int tid  = threadIdx.x;
    int row0 = blockIdx.x * 64;
#pragma unroll
    for (int q = 0; q < 8; q++) {
        int idx = tid + 256 * q;
        int r = idx >> 5, c4 = (idx & 31) * 4;
        float4 v = ld4(A + (size_t)(row0 + r) * K128 + c4);
        sth4(&Ah[r * AS + c4], v);
    }
#pragma unroll
    for (int q = 0; q < NCOL / 16; q++) {
        int idx = tid + 256 * q;
        int n = idx >> 4, c8 = (idx & 15) * 8;
        *(half8*)&Wh[n * AS + c8] = *(const half8*)(Wt + n * K128 + c8);
    }
    __syncthreads();

    int lane = tid & 63, wv = tid >> 6, m = lane & 15, quad = lane >> 4;
    f32x4 acc[NCOL / 16];
#pragma unroll
    for (int ct = 0; ct < NCOL / 16; ct++) acc[ct] = (f32x4){0.f, 0.f, 0.f, 0.f};
#pragma unroll
    for (int kt = 0; kt < 4; kt++) {
        half8 af = *(const half8*)&Ah[(wv * 16 + m) * AS + kt * 32 + quad * 8];
#pragma unroll
        for (int ct = 0; ct < NCOL / 16; ct++) {
            half8 bf = *(const half8*)&Wh[(ct * 16 + m) * AS + kt * 32 + quad * 8];
            acc[ct] = __builtin_amdgcn_mfma_f32_16x16x32_f16(af, bf, acc[ct], 0, 0, 0);
        }
    }
    float d[4];
#pragma unroll
    for (int r = 0; r < 4; r++) d[r] = dis[row0 + wv * 16 + quad * 4 + r];
#pragma unroll
    for (int ct = 0; ct < NCOL / 16; ct++)
#pragma unroll
        for (int r = 0; r < 4; r++) {
            int grow = row0 + wv * 16 + quad * 4 + r;
            out[(size_t)grow * NCOL + ct * 16 + m] = (_Float16)(acc[ct][r] * d[r]);
        }
}

// ------------------------------------------------- fused agg(F=128) + gemm2 (MFMA)
// 8 nodes/block, 32 threads/node = 2 edge-halves x 16 feature-threads.
// Halves process alternating edge-quads; partials combine via shfl_xor(16)
// (halves are lane-partners in the same wave64) -> no extra LDS/registers.
// Phase 2: MFMA on a 16-row A tile (rows 8..15 zeroed), writes guarded to 8.
__global__ __launch_bounds__(256) void k_agg_gemm(const _Float16* __restrict__ xw,
                                                  const float* __restrict__ dis,
                                                  const unsigned* __restrict__ edata,
                                                  const int* __restrict__ rs,
                                                  const float* __restrict__ bias,
                                                  const _Float16* __restrict__ Wt2,
                                                  _Float16* __restrict__ xw2, int N) {
    constexpr int F = 128, AS = 136;
    __shared__ _Float16 Hs[16 * AS];
    __shared__ _Float16 Ws[64 * AS];

    int tid   = threadIdx.x;
    int node0 = blockIdx.x * 8;
    int nl    = tid >> 5;            // 0..7
    int half  = (tid >> 4) & 1;      // 0/1 edge-half
    int node  = node0 + nl;
    int j8    = (tid & 15) * 8;

    // stage Wt2 (64 x 128 fp16)
#pragma unroll
    for (int q = 0; q < 4; q++) {
        int idx = tid + 256 * q;
        int n = idx >> 4, c8 = (idx & 15) * 8;
        *(half8*)&Ws[n * AS + c8] = *(const half8*)(Wt2 + n * K128 + c8);
    }
    // zero A-tile rows 8..15 (cols 0..127 are all MFMA reads touch)
    if (tid < 128) {
        int r = 8 + (tid >> 4), c8 = (tid & 15) * 8;
        half8 z = {};
        *(half8*)&Hs[r * AS + c8] = z;
    }

    // ---- phase 1: gather (this thread's half of the edge list).
    float a0[8], a1[8], a2[8], a3[8];
    {
#pragma unroll
        for (int t = 0; t < 8; t++) { a0[t] = 0.f; a1[t] = 0.f; a2[t] = 0.f; a3[t] = 0.f; }
        if (half == 0) {   // self-loop + bias only once
            float dv = dis[node];
            half8 sv = *(const half8*)(xw + (size_t)node * F + j8);
            float4 bA = ld4(bias + j8), bB = ld4(bias + j8 + 4);
#pragma unroll
            for (int t = 0; t < 4; t++) { a0[t] = (float)sv[t] * dv + (&bA.x)[t];
                                          a0[t + 4] = (float)sv[t + 4] * dv + (&bB.x)[t]; }
        }
    }
    int s = rs[node], e = rs[node + 1];
    for (int j = s + half * 4; j + 4 <= e; j += 8) {
        unsigned q0 = edata[j + 0], q1 = edata[j + 1], q2 = edata[j + 2], q3 = edata[j + 3];
        half8 v0 = *(const half8*)(xw + (size_t)(q0 >> 16) * F + j8);
        half8 v1 = *(const half8*)(xw + (size_t)(q1 >> 16) * F + j8);
        half8 v2 = *(const half8*)(xw + (size_t)(q2 >> 16) * F + j8);
        half8 v3 = *(const half8*)(xw + (size_t)(q3 >> 16) * F + j8);
        float n0 = unpack_w(q0), n1 = unpack_w(q1), n2 = unpack_w(q2), n3 = unpack_w(q3);
#pragma unroll
        for (int t = 0; t < 8; t++) {
            a0[t] += n0 * (float)v0[t];
            a1[t] += n1 * (float)v1[t];
            a2[t] += n2 * (float)v2[t];
            a3[t] += n3 * (float)v3[t];
        }
    }
    if (half == 0) {   // tail (<4 edges)
        for (int j = e - ((e - s) & 3); j < e; j++) {
            unsigned q = edata[j];
            half8 v = *(const half8*)(xw + (size_t)(q >> 16) * F + j8);
            float nm = unpack_w(q);
#pragma unroll
            for (int t = 0; t < 8; t++) a0[t] += nm * (float)v[t];
        }
    }
    // combine halves via lane-partner shuffle, then relu -> Hs (half 0 writes)
    float sum[8];
#pragma unroll
    for (int t = 0; t < 8; t++) {
        float v = (a0[t] + a1[t]) + (a2[t] + a3[t]);
        sum[t] = v + __shfl_xor(v, 16);
    }
    if (half == 0) {
        half8 hv;
#pragma unroll
        for (int t = 0; t < 8; t++) hv[t] = (_Float16)fmaxf(sum[t], 0.f);
        *(half8*)&Hs[nl * AS + j8] = hv;
    }
    __syncthreads();

    // ---- phase 2: MFMA. wave wv -> cols wv*16..+15 of the 16-row tile.
    int lane = tid & 63, wv = tid >> 6, m = lane & 15, quad = lane >> 4;
    f32x4 acc = (f32x4){0.f, 0.f, 0.f, 0.f};
#pragma unroll
    for (int kt = 0; kt < 4; kt++) {
        half8 af = *(const half8*)&Hs[m * AS + kt * 32 + quad * 8];
        half8 bf = *(const half8*)&Ws[(wv * 16 + m) * AS + kt * 32 + quad * 8];
        acc = __builtin_amdgcn_mfma_f32_16x16x32_f16(af, bf, acc, 0, 0, 0);
    }
#pragma unroll
    for (int r = 0; r < 4; r++) {
        int lr = quad * 4 + r;
        if (lr < 8) {
            int gn = node0 + lr;
            xw2[(size_t)gn * 64 + wv * 16 + m] = (_Float16)(acc[r] * dis[gn]);
        }
    }
}

// ------------------------------------------------- agg F=64 fused with mean-pool
// 32 nodes/block, 8 threads/node, half8 (16B) gathers: same bytes as before,
// half the gather instructions.
__global__ __launch_bounds__(256) void k_agg_pool(const _Float16* __restrict__ xw,
                                                  const float* __restrict__ dis,
                                                  const unsigned* __restrict__ edata,
                                                  const int* __restrict__ rs,
                                                  const float* __restrict__ bias,
                                                  const int* __restrict__ batch,
                                                  float* __restrict__ g,
                                                  int* __restrict__ gcnt, int N) {
    constexpr int F = 64;
    __shared__ float T[32][F + 4];
    __shared__ int sb[32];
    int tid  = threadIdx.x;
    int base = blockIdx.x * 32;
    int nl   = tid >> 3;           // 0..31
    int node = base + nl;
    int j8   = (tid & 7) * 8;
    if (tid < 32) sb[tid] = batch[base + tid];

    float dv = dis[node];
    half8 sv = *(const half8*)(xw + (size_t)node * F + j8);
    float4 bA = ld4(bias + j8), bB = ld4(bias + j8 + 4);
    float a0[8], a1[8], a2[8], a3[8];
#pragma unroll
    for (int t = 0; t < 4; t++) { a0[t] = (float)sv[t] * dv + (&bA.x)[t];
                                  a0[t + 4] = (float)sv[t + 4] * dv + (&bB.x)[t]; }
#pragma unroll
    for (int t = 0; t < 8; t++) { a1[t] = 0.f; a2[t] = 0.f; a3[t] = 0.f; }
    int s = rs[node], e = rs[node + 1];
    int j = s;
    for (; j + 4 <= e; j += 4) {
        unsigned q0 = edata[j + 0], q1 = edata[j + 1], q2 = edata[j + 2], q3 = edata[j + 3];
        half8 v0 = *(const half8*)(xw + (size_t)(q0 >> 16) * F + j8);
        half8 v1 = *(const half8*)(xw + (size_t)(q1 >> 16) * F + j8);
        half8 v2 = *(const half8*)(xw + (size_t)(q2 >> 16) * F + j8);
        half8 v3 = *(const half8*)(xw + (size_t)(q3 >> 16) * F + j8);
        float n0 = unpack_w(q0), n1 = unpack_w(q1), n2 = unpack_w(q2), n3 = unpack_w(q3);
#pragma unroll
        for (int t = 0; t < 8; t++) {
            a0[t] += n0 * (float)v0[t];
            a1[t] += n1 * (float)v1[t];
            a2[t] += n2 * (float)v2[t];
            a3[t] += n3 * (float)v3[t];
        }
    }
    for (; j < e; j++) {
        unsigned q = edata[j];
        half8 v = *(const half8*)(xw + (size_t)(q >> 16) * F + j8);
        float nm = unpack_w(q);
#pragma unroll
        for (int t = 0; t < 8; t++) a0[t] += nm * (float)v[t];
    }
#pragma unroll
    for (int t = 0; t < 8; t++)
        T[nl][j8 + t] = fmaxf((a0[t] + a1[t]) + (a2[t] + a3[t]), 0.f);
    __syncthreads();
    if (tid < 64) {
        int f = tid;
        float run = 0.f;
        int cur = -1, cnt = 0;
        for (int k = 0; k < 32; k++) {
            int bb = sb[k];
            if (bb != cur) {
                if (cur >= 0) {
                    atomicAdd(&g[cur * 64 + f], run);
                    if (f == 0) atomicAdd(&gcnt[cur], cnt);
                }
                cur = bb; run = 0.f; cnt = 0;
            }
            run += T[k][f];
            cnt++;
        }
        atomicAdd(&g[cur * 64 + f], run);
        if (f == 0) atomicAdd(&gcnt[cur], cnt);
    }
}

// ------------------------------------------------- FC: out[NG,FLAT] = (g/cnt) @ Wfc + bfc
__global__ __launch_bounds__(256) void k_fc(const float* __restrict__ g,
                                            const int* __restrict__ gcnt,
                                            const float* __restrict__ Wfc,
                                            const float* __restrict__ bfc,
                                            float* __restrict__ out) {
    __shared__ float gs[64];
    int i = blockIdx.y;
    int j = blockIdx.x * blockDim.x + threadIdx.x;
    if (threadIdx.x < 64) {
        float c = (float)gcnt[i];
        gs[threadIdx.x] = g[i * 64 + threadIdx.x] / fmaxf(c, 1.0f);
    }
    __syncthreads();
    if (j >= FLAT) return;
    float acc = bfc[j];
#pragma unroll 8
    for (int k = 0; k < 64; k++) acc += gs[k] * Wfc[k * FLAT + j];
    out[(size_t)i * FLAT + j] = acc;
}

// ================================================================ launcher
extern "C" void kernel_launch(void* const* d_in, const int* in_sizes, int n_in,
                              void* d_out, int out_size, void* d_ws, size_t ws_size,
                              hipStream_t stream) {
    const float* x    = (const float*)d_in[0];
    const int*   ei   = (const int*)d_in[1];
    const float* ew   = (const float*)d_in[2];
    const int*   batch= (const int*)d_in[3];
    const float* W1   = (const float*)d_in[4];
    const float* b1   = (const float*)d_in[5];
    const float* W2   = (const float*)d_in[6];
    const float* b2   = (const float*)d_in[7];
    const float* Wfc  = (const float*)d_in[8];
    const float* bfc  = (const float*)d_in[9];
    float* out = (float*)d_out;

    const int N = in_sizes[0] / K128;   // 40000
    const int E = in_sizes[2];          // 640000
    const int* row = ei;
    const int* col = ei + E;
    const int nbk = (N + BKB - 1) / BKB;   // 157 buckets
    const int neb = (E + 1023) / 1024;     // edge-chunk blocks

    // ---- workspace carve (256B aligned)
    char* p = (char*)d_ws;
    auto alloc = [&](size_t bytes) -> void* {
        void* r = (void*)p;
        p += (bytes + 255) & ~(size_t)255;
        return r;
    };
    float*     dis   = (float*)    alloc((size_t)N * 4);
    int*       rs    = (int*)      alloc((size_t)(N + 1) * 4);
    uint2*     bk    = (uint2*)    alloc((size_t)E * 8);
    unsigned*  edata = (unsigned*) alloc((size_t)E * 4);
    _Float16*  xw1   = (_Float16*) alloc((size_t)N * 128 * 2);
    _Float16*  xw2   = (_Float16*) alloc((size_t)N * 64 * 2);
    _Float16*  Wt1   = (_Float16*) alloc((size_t)128 * 128 * 2);
    _Float16*  Wt2   = (_Float16*) alloc((size_t)64 * 128 * 2);
    float*     g     = (float*)    alloc(64 * 64 * 4);
    int*       gcnt  = (int*)      alloc(64 * 4);
    int*       bhist = (int*)      alloc(BKB * 4);
    int*       bcur  = (int*)      alloc(BKB * 4);

    // ---- 8 dispatches total
    k_init     <<<96,  256, 0, stream>>>(bhist, bcur, g, gcnt, W1, W2, Wt1, Wt2);
    k_bhist    <<<neb, 256, 0, stream>>>(col, bhist, E, nbk);
    k_bucket   <<<neb, 256, 0, stream>>>(row, col, ew, bhist, bcur, bk, E, nbk);
    k_colsedata<<<nbk, 256, 0, stream>>>(bk, bhist, dis, rs, edata, N, E, nbk);

    k_gemm1    <<<N / 64, 256, 0, stream>>>(x, Wt1, dis, xw1, N);
    k_agg_gemm <<<N / 8,  256, 0, stream>>>(xw1, dis, edata, rs, b1, Wt2, xw2, N);
    k_agg_pool <<<N / 32, 256, 0, stream>>>(xw2, dis, edata, rs, b2, batch, g, gcnt, N);

    dim3 fcg((FLAT + 255) / 256, NG);
    k_fc<<<fcg, 256, 0, stream>>>(g, gcnt, Wfc, bfc, out);
}

// Round 10
// 169.579 us; speedup vs baseline: 1.1371x; 1.1371x over previous
//
#include <hip/hip_runtime.h>
#include <hip/hip_bf16.h>
#include <hip/hip_fp16.h>
#include <type_traits>

#define NG 64          // number of graphs
#define FLAT 2904      // FC output width
#define K128 128       // inner dim for both GEMMs
#define BKB 256        // cols per bucket (col >> 8)
#define BCAP 4608      // fixed bucket capacity (mean 4096, +8 sigma)

typedef _Float16 h4 __attribute__((ext_vector_type(4)));     // 8B
typedef _Float16 half8 __attribute__((ext_vector_type(8)));  // 16B MFMA frag
typedef float f32x4 __attribute__((ext_vector_type(4)));

// ---------------------------------------------------------------- utilities
__device__ __forceinline__ float4 ld4(const float* p) { return *(const float4*)p; }
__device__ __forceinline__ float4 ldh4(const _Float16* p) {
    h4 h = *(const h4*)p;
    return make_float4((float)h.x, (float)h.y, (float)h.z, (float)h.w);
}
__device__ __forceinline__ void sth4(_Float16* p, float4 v) {
    h4 h; h.x = (_Float16)v.x; h.y = (_Float16)v.y; h.z = (_Float16)v.z; h.w = (_Float16)v.w;
    *(h4*)p = h;
}
__device__ __forceinline__ float unpack_w(unsigned q) {
    return (float)__builtin_bit_cast(_Float16, (unsigned short)(q & 0xFFFFu));
}

// ------------------------------------------------- init: zero accum + both W converts
// block 0 zeroes bcursor/g/gcnt; all 96 blocks share the wconv work.
__global__ __launch_bounds__(256) void k_init(int* __restrict__ bcursor,
                                              float* __restrict__ g,
                                              int* __restrict__ gcnt,
                                              const float* __restrict__ W1,
                                              const float* __restrict__ W2,
                                              _Float16* __restrict__ Wt1,
                                              _Float16* __restrict__ Wt2) {
    int tid = threadIdx.x;
    if (blockIdx.x == 0) {
        bcursor[tid] = 0;
        for (int i = tid; i < NG * 64; i += 256) g[i] = 0.f;
        if (tid < NG) gcnt[tid] = 0;
    }
    int idx = blockIdx.x * 256 + tid;
    if (idx < 128 * 128) {
        int n = idx % 128, k = idx / 128;
        Wt1[n * K128 + k] = (_Float16)W1[k * 128 + n];
    } else if (idx < 128 * 128 + 64 * 128) {
        int i = idx - 128 * 128;
        int n = i % 64, k = i / 64;
        Wt2[n * K128 + k] = (_Float16)W2[k * 64 + n];
    }
}

// ================================================================ CSR build
// Fixed-capacity bucket sort: no histogram pre-pass, no scan in k_bucket.
// bk is bucket-strided (bucket b at [b*BCAP, b*BCAP+size_b)); sizes in bcursor.
// edata = (row<<16)|fp16(w'), w' = ew*dis[col].

__global__ __launch_bounds__(256) void k_bucket(const int* __restrict__ row,
                                                const int* __restrict__ col,
                                                const float* __restrict__ ew,
                                                int* __restrict__ bcursor,
                                                uint2* __restrict__ bk, int E, int nbk) {
    __shared__ int h[BKB];
    __shared__ int cur[BKB];
    int tid = threadIdx.x;
    h[tid] = 0;
    __syncthreads();
    int base = blockIdx.x * 1024 + tid * 4;
    int c[4];
#pragma unroll
    for (int q = 0; q < 4; q++) {
        int e = base + q;
        c[q] = (e < E) ? col[e] : -1;
        if (c[q] >= 0) atomicAdd(&h[c[q] >> 8], 1);
    }
    __syncthreads();
    if (tid < nbk) cur[tid] = h[tid] ? tid * BCAP + atomicAdd(&bcursor[tid], h[tid]) : 0;
    __syncthreads();
#pragma unroll
    for (int q = 0; q < 4; q++) {
        int e = base + q;
        if (c[q] >= 0) {
            int slot = atomicAdd(&cur[c[q] >> 8], 1);
            bk[slot] = make_uint2(((unsigned)c[q] << 16) | (unsigned)row[e],
                                  __float_as_uint(ew[e]));
        }
    }
}

// ---- fused: bucket sizes (shuffle scan -> compact bases) -> degree/count
//      -> dis/rs -> edata. 8-way batched pass-1 loads; LDS edge cache.
__global__ __launch_bounds__(256) void k_colsedata(const uint2* __restrict__ bk,
                                                   const int* __restrict__ bsz,
                                                   float* __restrict__ dis,
                                                   int* __restrict__ rs,
                                                   unsigned* __restrict__ edata,
                                                   int N, int E, int nbk) {
    constexpr int CAP = 5120;          // 40 KB LDS edge cache (mean bucket 4096)
    __shared__ float sdeg[BKB];
    __shared__ int scnt[BKB];
    __shared__ int cur[BKB];
    __shared__ float sdis[BKB];
    __shared__ int wsum[4];
    __shared__ int sse[2];
    __shared__ uint2 ebuf[CAP];
    int b = blockIdx.x, tid = threadIdx.x;
    int lane = tid & 63, wv = tid >> 6;
    int gh = (tid < nbk) ? bsz[tid] : 0;   // bucket sizes
    sdeg[tid] = 0.f; scnt[tid] = 0;

    // ---- scan 1: inclusive scan of bucket sizes (shuffle-based) -> compact bases
    int v = gh;
#pragma unroll
    for (int off = 1; off < 64; off <<= 1) {
        int t = __shfl_up(v, off);
        if (lane >= off) v += t;
    }
    if (lane == 63) wsum[wv] = v;
    __syncthreads();
    if (wv > 0) {
        int add = 0;
        for (int k = 0; k < wv; k++) add += wsum[k];
        v += add;
    }
    if (tid == b) { sse[0] = v - gh; sse[1] = v; }
    __syncthreads();
    int s = sse[0], e = sse[1];
    int n = e - s;
    size_t src = (size_t)b * BCAP;

    // ---- pass 1: 8 independent loads in flight per iteration; LDS cache; deg/cnt
    for (int i0 = tid; i0 < n; i0 += 2048) {
        uint2 q[8]; bool gv[8];
#pragma unroll
        for (int u = 0; u < 8; u++) {
            int i = i0 + u * 256;
            gv[u] = i < n;
            if (gv[u]) q[u] = bk[src + i];
        }
#pragma unroll
        for (int u = 0; u < 8; u++) {
            if (gv[u]) {
                int i = i0 + u * 256;
                if (i < CAP) ebuf[i] = q[u];
                int c8 = (q[u].x >> 16) & 255;
                atomicAdd(&sdeg[c8], __uint_as_float(q[u].y));
                atomicAdd(&scnt[c8], 1);
            }
        }
    }
    __syncthreads();

    // ---- scan 2: inclusive scan of per-col counts (shuffle-based)
    int cnt = scnt[tid];
    int v2 = cnt;
#pragma unroll
    for (int off = 1; off < 64; off <<= 1) {
        int t = __shfl_up(v2, off);
        if (lane >= off) v2 += t;
    }
    if (lane == 63) wsum[wv] = v2;
    __syncthreads();
    if (wv > 0) {
        int add = 0;
        for (int k = 0; k < wv; k++) add += wsum[k];
        v2 += add;
    }
    float d  = rsqrtf(sdeg[tid] + 1.0f);
    int   r0 = s + v2 - cnt;
    int gcol = b * BKB + tid;
    if (gcol < N) { dis[gcol] = d; rs[gcol] = r0; }
    if (b == 0 && tid == 0) rs[N] = E;
    cur[tid] = r0; sdis[tid] = d;
    __syncthreads();

    // ---- pass 2: from LDS cache (fallback to global beyond CAP)
    for (int i = tid; i < n; i += 256) {
        uint2 q = (i < CAP) ? ebuf[i] : bk[src + i];
        int c8 = (q.x >> 16) & 255;
        unsigned r = q.x & 0xFFFFu;
        _Float16 wh = (_Float16)(__uint_as_float(q.y) * sdis[c8]);  // ew*dis[col]
        int pos = atomicAdd(&cur[c8], 1);
        edata[pos] = (r << 16) | (unsigned)__builtin_bit_cast(unsigned short, wh);
    }
}

// ------------------------------------------------- MFMA fp16 GEMM (layer1), dis epilogue
// out[r] = dis[r] * (A[r] @ W)  stored fp16.
__global__ __launch_bounds__(256) void k_gemm1(const float* __restrict__ A,
                                               const _Float16* __restrict__ Wt,
                                               const float* __restrict__ dis,
                                               _Float16* __restrict__ out, int M) {
    constexpr int NCOL = 128, AS = 136;
    __shared__ _Float16 Ah[64 * AS];
    __shared__ _Float16 Wh[NCOL * AS];

    int tid  = threadIdx.x;
    int row0 = blockIdx.x * 64;
#pragma unroll
    for (int q = 0; q < 8; q++) {
        int idx = tid + 256 * q;
        int r = idx >> 5, c4 = (idx & 31) * 4;
        float4 v = ld4(A + (size_t)(row0 + r) * K128 + c4);
        sth4(&Ah[r * AS + c4], v);
    }
#pragma unroll
    for (int q = 0; q < NCOL / 16; q++) {
        int idx = tid + 256 * q;
        int n = idx >> 4, c8 = (idx & 15) * 8;
        *(half8*)&Wh[n * AS + c8] = *(const half8*)(Wt + n * K128 + c8);
    }
    __syncthreads();

    int lane = tid & 63, wv = tid >> 6, m = lane & 15, quad = lane >> 4;
    f32x4 acc[NCOL / 16];
#pragma unroll
    for (int ct = 0; ct < NCOL / 16; ct++) acc[ct] = (f32x4){0.f, 0.f, 0.f, 0.f};
#pragma unroll
    for (int kt = 0; kt < 4; kt++) {
        half8 af = *(const half8*)&Ah[(wv * 16 + m) * AS + kt * 32 + quad * 8];
#pragma unroll
        for (int ct = 0; ct < NCOL / 16; ct++) {
            half8 bf = *(const half8*)&Wh[(ct * 16 + m) * AS + kt * 32 + quad * 8];
            acc[ct] = __builtin_amdgcn_mfma_f32_16x16x32_f16(af, bf, acc[ct], 0, 0, 0);
        }
    }
    float d[4];
#pragma unroll
    for (int r = 0; r < 4; r++) d[r] = dis[row0 + wv * 16 + quad * 4 + r];
#pragma unroll
    for (int ct = 0; ct < NCOL / 16; ct++)
#pragma unroll
        for (int r = 0; r < 4; r++) {
            int grow = row0 + wv * 16 + quad * 4 + r;
            out[(size_t)grow * NCOL + ct * 16 + m] = (_Float16)(acc[ct][r] * d[r]);
        }
}

// ------------------------------------------------- fused agg(F=128) + gemm2 (MFMA)
// 16 nodes/block. Phase 1: gather h1 rows (relu) into LDS tile (h1 never hits
// memory). Phase 2: xw2[16x64] = dis * (h1_tile @ W2) via 16x16x32 MFMA,
// each wave one 16-col strip of the shared 16-row A-tile.
__global__ __launch_bounds__(256) void k_agg_gemm(const _Float16* __restrict__ xw,
                                                  const float* __restrict__ dis,
                                                  const unsigned* __restrict__ edata,
                                                  const int* __restrict__ rs,
                                                  const float* __restrict__ bias,
                                                  const _Float16* __restrict__ Wt2,
                                                  _Float16* __restrict__ xw2, int N) {
    constexpr int F = 128, AS = 136;
    __shared__ _Float16 Hs[16 * AS];
    __shared__ _Float16 Ws[64 * AS];

    int tid   = threadIdx.x;
    int node0 = blockIdx.x * 16;
    int nl    = tid >> 4;            // 0..15
    int node  = node0 + nl;
    int j8    = (tid & 15) * 8;

    // stage Wt2 (64 x 128 fp16)
#pragma unroll
    for (int q = 0; q < 4; q++) {
        int idx = tid + 256 * q;
        int n = idx >> 4, c8 = (idx & 15) * 8;
        *(half8*)&Ws[n * AS + c8] = *(const half8*)(Wt2 + n * K128 + c8);
    }

    // ---- phase 1: gather. 4 independent accumulators x 8 features.
    float a0[8], a1[8], a2[8], a3[8];
    {
        float dv = dis[node];
        half8 sv = *(const half8*)(xw + (size_t)node * F + j8);
        float4 bA = ld4(bias + j8), bB = ld4(bias + j8 + 4);
#pragma unroll
        for (int t = 0; t < 4; t++) { a0[t] = (float)sv[t] * dv + (&bA.x)[t];
                                      a0[t + 4] = (float)sv[t + 4] * dv + (&bB.x)[t]; }
#pragma unroll
        for (int t = 0; t < 8; t++) { a1[t] = 0.f; a2[t] = 0.f; a3[t] = 0.f; }
    }
    int s = rs[node], e = rs[node + 1];
    int j = s;
    for (; j + 4 <= e; j += 4) {
        unsigned q0 = edata[j + 0], q1 = edata[j + 1], q2 = edata[j + 2], q3 = edata[j + 3];
        half8 v0 = *(const half8*)(xw + (size_t)(q0 >> 16) * F + j8);
        half8 v1 = *(const half8*)(xw + (size_t)(q1 >> 16) * F + j8);
        half8 v2 = *(const half8*)(xw + (size_t)(q2 >> 16) * F + j8);
        half8 v3 = *(const half8*)(xw + (size_t)(q3 >> 16) * F + j8);
        float n0 = unpack_w(q0), n1 = unpack_w(q1), n2 = unpack_w(q2), n3 = unpack_w(q3);
#pragma unroll
        for (int t = 0; t < 8; t++) {
            a0[t] += n0 * (float)v0[t];
            a1[t] += n1 * (float)v1[t];
            a2[t] += n2 * (float)v2[t];
            a3[t] += n3 * (float)v3[t];
        }
    }
    for (; j < e; j++) {
        unsigned q = edata[j];
        half8 v = *(const half8*)(xw + (size_t)(q >> 16) * F + j8);
        float nm = unpack_w(q);
#pragma unroll
        for (int t = 0; t < 8; t++) a0[t] += nm * (float)v[t];
    }
    half8 hv;
#pragma unroll
    for (int t = 0; t < 8; t++)
        hv[t] = (_Float16)fmaxf((a0[t] + a1[t]) + (a2[t] + a3[t]), 0.f);
    *(half8*)&Hs[nl * AS + j8] = hv;
    __syncthreads();

    // ---- phase 2: MFMA. wave wv -> cols wv*16..+15 of the 16-row tile.
    int lane = tid & 63, wv = tid >> 6, m = lane & 15, quad = lane >> 4;
    f32x4 acc = (f32x4){0.f, 0.f, 0.f, 0.f};
#pragma unroll
    for (int kt = 0; kt < 4; kt++) {
        half8 af = *(const half8*)&Hs[m * AS + kt * 32 + quad * 8];
        half8 bf = *(const half8*)&Ws[(wv * 16 + m) * AS + kt * 32 + quad * 8];
        acc = __builtin_amdgcn_mfma_f32_16x16x32_f16(af, bf, acc, 0, 0, 0);
    }
#pragma unroll
    for (int r = 0; r < 4; r++) {
        int gn = node0 + quad * 4 + r;
        xw2[(size_t)gn * 64 + wv * 16 + m] = (_Float16)(acc[r] * dis[gn]);
    }
}

// ------------------------------------------------- agg F=64 fused with mean-pool
// 32 nodes/block, 8 threads/node, half8 (16B) gathers.
__global__ __launch_bounds__(256) void k_agg_pool(const _Float16* __restrict__ xw,
                                                  const float* __restrict__ dis,
                                                  const unsigned* __restrict__ edata,
                                                  const int* __restrict__ rs,
                                                  const float* __restrict__ bias,
                                                  const int* __restrict__ batch,
                                                  float* __restrict__ g,
                                                  int* __restrict__ gcnt, int N) {
    constexpr int F = 64;
    __shared__ float T[32][F + 4];
    __shared__ int sb[32];
    int tid  = threadIdx.x;
    int base = blockIdx.x * 32;
    int nl   = tid >> 3;           // 0..31
    int node = base + nl;
    int j8   = (tid & 7) * 8;
    if (tid < 32) sb[tid] = batch[base + tid];

    float dv = dis[node];
    half8 sv = *(const half8*)(xw + (size_t)node * F + j8);
    float4 bA = ld4(bias + j8), bB = ld4(bias + j8 + 4);
    float a0[8], a1[8], a2[8], a3[8];
#pragma unroll
    for (int t = 0; t < 4; t++) { a0[t] = (float)sv[t] * dv + (&bA.x)[t];
                                  a0[t + 4] = (float)sv[t + 4] * dv + (&bB.x)[t]; }
#pragma unroll
    for (int t = 0; t < 8; t++) { a1[t] = 0.f; a2[t] = 0.f; a3[t] = 0.f; }
    int s = rs[node], e = rs[node + 1];
    int j = s;
    for (; j + 4 <= e; j += 4) {
        unsigned q0 = edata[j + 0], q1 = edata[j + 1], q2 = edata[j + 2], q3 = edata[j + 3];
        half8 v0 = *(const half8*)(xw + (size_t)(q0 >> 16) * F + j8);
        half8 v1 = *(const half8*)(xw + (size_t)(q1 >> 16) * F + j8);
        half8 v2 = *(const half8*)(xw + (size_t)(q2 >> 16) * F + j8);
        half8 v3 = *(const half8*)(xw + (size_t)(q3 >> 16) * F + j8);
        float n0 = unpack_w(q0), n1 = unpack_w(q1), n2 = unpack_w(q2), n3 = unpack_w(q3);
#pragma unroll
        for (int t = 0; t < 8; t++) {
            a0[t] += n0 * (float)v0[t];
            a1[t] += n1 * (float)v1[t];
            a2[t] += n2 * (float)v2[t];
            a3[t] += n3 * (float)v3[t];
        }
    }
    for (; j < e; j++) {
        unsigned q = edata[j];
        half8 v = *(const half8*)(xw + (size_t)(q >> 16) * F + j8);
        float nm = unpack_w(q);
#pragma unroll
        for (int t = 0; t < 8; t++) a0[t] += nm * (float)v[t];
    }
#pragma unroll
    for (int t = 0; t < 8; t++)
        T[nl][j8 + t] = fmaxf((a0[t] + a1[t]) + (a2[t] + a3[t]), 0.f);
    __syncthreads();
    if (tid < 64) {
        int f = tid;
        float run = 0.f;
        int cur = -1, cnt = 0;
        for (int k = 0; k < 32; k++) {
            int bb = sb[k];
            if (bb != cur) {
                if (cur >= 0) {
                    atomicAdd(&g[cur * 64 + f], run);
                    if (f == 0) atomicAdd(&gcnt[cur], cnt);
                }
                cur = bb; run = 0.f; cnt = 0;
            }
            run += T[k][f];
            cnt++;
        }
        atomicAdd(&g[cur * 64 + f], run);
        if (f == 0) atomicAdd(&gcnt[cur], cnt);
    }
}

// ------------------------------------------------- FC: out[NG,FLAT] = (g/cnt) @ Wfc + bfc
__global__ __launch_bounds__(256) void k_fc(const float* __restrict__ g,
                                            const int* __restrict__ gcnt,
                                            const float* __restrict__ Wfc,
                                            const float* __restrict__ bfc,
                                            float* __restrict__ out) {
    __shared__ float gs[64];
    int i = blockIdx.y;
    int j = blockIdx.x * blockDim.x + threadIdx.x;
    if (threadIdx.x < 64) {
        float c = (float)gcnt[i];
        gs[threadIdx.x] = g[i * 64 + threadIdx.x] / fmaxf(c, 1.0f);
    }
    __syncthreads();
    if (j >= FLAT) return;
    float acc = bfc[j];
#pragma unroll 8
    for (int k = 0; k < 64; k++) acc += gs[k] * Wfc[k * FLAT + j];
    out[(size_t)i * FLAT + j] = acc;
}

// ================================================================ launcher
extern "C" void kernel_launch(void* const* d_in, const int* in_sizes, int n_in,
                              void* d_out, int out_size, void* d_ws, size_t ws_size,
                              hipStream_t stream) {
    const float* x    = (const float*)d_in[0];
    const int*   ei   = (const int*)d_in[1];
    const float* ew   = (const float*)d_in[2];
    const int*   batch= (const int*)d_in[3];
    const float* W1   = (const float*)d_in[4];
    const float* b1   = (const float*)d_in[5];
    const float* W2   = (const float*)d_in[6];
    const float* b2   = (const float*)d_in[7];
    const float* Wfc  = (const float*)d_in[8];
    const float* bfc  = (const float*)d_in[9];
    float* out = (float*)d_out;

    const int N = in_sizes[0] / K128;   // 40000
    const int E = in_sizes[2];          // 640000
    const int* row = ei;
    const int* col = ei + E;
    const int nbk = (N + BKB - 1) / BKB;   // 157 buckets
    const int neb = (E + 1023) / 1024;     // edge-chunk blocks

    // ---- workspace carve (256B aligned)
    char* p = (char*)d_ws;
    auto alloc = [&](size_t bytes) -> void* {
        void* r = (void*)p;
        p += (bytes + 255) & ~(size_t)255;
        return r;
    };
    float*     dis   = (float*)    alloc((size_t)N * 4);
    int*       rs    = (int*)      alloc((size_t)(N + 1) * 4);
    uint2*     bk    = (uint2*)    alloc((size_t)nbk * BCAP * 8);
    unsigned*  edata = (unsigned*) alloc((size_t)E * 4);
    _Float16*  xw1   = (_Float16*) alloc((size_t)N * 128 * 2);
    _Float16*  xw2   = (_Float16*) alloc((size_t)N * 64 * 2);
    _Float16*  Wt1   = (_Float16*) alloc((size_t)128 * 128 * 2);
    _Float16*  Wt2   = (_Float16*) alloc((size_t)64 * 128 * 2);
    float*     g     = (float*)    alloc(64 * 64 * 4);
    int*       gcnt  = (int*)      alloc(64 * 4);
    int*       bcur  = (int*)      alloc(BKB * 4);

    // ---- 7 dispatches total
    k_init     <<<96,  256, 0, stream>>>(bcur, g, gcnt, W1, W2, Wt1, Wt2);
    k_bucket   <<<neb, 256, 0, stream>>>(row, col, ew, bcur, bk, E, nbk);
    k_colsedata<<<nbk, 256, 0, stream>>>(bk, bcur, dis, rs, edata, N, E, nbk);

    k_gemm1    <<<N / 64, 256, 0, stream>>>(x, Wt1, dis, xw1, N);
    k_agg_gemm <<<N / 16, 256, 0, stream>>>(xw1, dis, edata, rs, b1, Wt2, xw2, N);
    k_agg_pool <<<N / 32, 256, 0, stream>>>(xw2, dis, edata, rs, b2, batch, g, gcnt, N);

    dim3 fcg((FLAT + 255) / 256, NG);
    k_fc<<<fcg, 256, 0, stream>>>(g, gcnt, Wfc, bfc, out);
}